// Round 2
// baseline (101.149 us; speedup 1.0000x reference)
//
#include <hip/hip_runtime.h>

// Morph2D soft rank-order filter:
//   patches(3x3, zero-pad SAME) * se -> sort ascending -> dot softmax(rank)
// x: [32,512,512,1] fp32, se: [3,3] fp32, rank: [9] fp32, out: same as x.
//
// One thread = 2 rows x 4 cols (8 px). Branchless padded loads (clamped
// address + select-zero) so all 12 global loads issue before one waitcnt.
// XCD swizzle: each XCD gets a contiguous 4-image chunk (~4MB = its L2).

#define BB 32
#define HH 512
#define WW 512

#define CSWAP(a,b) { float lo_ = fminf(v[a], v[b]); float hi_ = fmaxf(v[a], v[b]); v[a] = lo_; v[b] = hi_; }

__global__ __launch_bounds__(256) void morph2d_kernel(
    const float* __restrict__ x, const float* __restrict__ se9,
    const float* __restrict__ rank, float* __restrict__ out)
{
    // XCD-aware swizzle: logical block id -> contiguous chunks per XCD
    int nper = gridDim.x >> 3;                       // blocks per XCD chunk
    int lb   = (blockIdx.x & 7) * nper + (blockIdx.x >> 3);
    int g    = lb * 256 + threadIdx.x;               // 1,048,576 total, exact

    int gx = g & 127;            // 128 x-groups of 4 px
    int yg = (g >> 7) & 255;     // 256 y-groups of 2 rows
    int b  = g >> 15;            // batch
    int x4 = gx << 2;
    int y0 = yg << 1;

    // inline softmax(rank) + se (uniform; values identical across lanes)
    float se[9], w[9];
    {
        float r[9]; float m = -3.4e38f;
        #pragma unroll
        for (int i = 0; i < 9; ++i) { r[i] = rank[i]; m = fmaxf(m, r[i]); }
        float s = 0.f;
        #pragma unroll
        for (int i = 0; i < 9; ++i) { r[i] = __expf(r[i] - m); s += r[i]; }
        float inv = 1.0f / s;
        #pragma unroll
        for (int i = 0; i < 9; ++i) { w[i] = r[i] * inv; se[i] = se9[i]; }
    }

    // Load 4 rows x 6 cols, branchless: clamp addresses, zero via select.
    const float* img = x + (size_t)b * (HH * WW);
    float rv[4][6];
    #pragma unroll
    for (int r = 0; r < 4; ++r) {
        int ry  = y0 - 1 + r;
        int ryc = min(max(ry, 0), HH - 1);
        const float* row = img + ryc * WW;
        float4 c  = *(const float4*)(row + x4);
        float  lf = row[max(x4 - 1, 0)];
        float  rt = row[min(x4 + 4, WW - 1)];
        float  m  = (ry >= 0 && ry < HH) ? 1.0f : 0.0f;
        rv[r][0] = ((x4 == 0)       ? 0.f : lf) * m;
        rv[r][1] = c.x * m;
        rv[r][2] = c.y * m;
        rv[r][3] = c.z * m;
        rv[r][4] = c.w * m;
        rv[r][5] = ((x4 + 4 >= WW)  ? 0.f : rt) * m;
    }

    #pragma unroll
    for (int r = 0; r < 2; ++r) {
        float4 res;
        float* resp = &res.x;
        #pragma unroll
        for (int j = 0; j < 4; ++j) {
            float v[9];
            #pragma unroll
            for (int dy = 0; dy < 3; ++dy) {
                v[dy*3+0] = rv[r+dy][j]   * se[dy*3+0];
                v[dy*3+1] = rv[r+dy][j+1] * se[dy*3+1];
                v[dy*3+2] = rv[r+dy][j+2] * se[dy*3+2];
            }
            // optimal 9-input sorting network: 25 CE, depth 7
            CSWAP(0,3) CSWAP(1,7) CSWAP(2,5) CSWAP(4,8)
            CSWAP(0,7) CSWAP(2,4) CSWAP(3,8) CSWAP(5,6)
            CSWAP(0,2) CSWAP(1,3) CSWAP(4,5) CSWAP(7,8)
            CSWAP(1,4) CSWAP(3,6) CSWAP(5,7)
            CSWAP(0,1) CSWAP(2,4) CSWAP(3,5) CSWAP(6,8)
            CSWAP(2,3) CSWAP(4,5) CSWAP(6,7)
            CSWAP(1,2) CSWAP(3,4) CSWAP(5,6)

            float acc = 0.f;
            #pragma unroll
            for (int i = 0; i < 9; ++i) acc = fmaf(v[i], w[i], acc);
            resp[j] = acc;
        }
        *(float4*)(out + (((size_t)b * HH + (y0 + r)) * WW + x4)) = res;
    }
}

extern "C" void kernel_launch(void* const* d_in, const int* in_sizes, int n_in,
                              void* d_out, int out_size, void* d_ws, size_t ws_size,
                              hipStream_t stream) {
    const float* x    = (const float*)d_in[0];
    const float* se   = (const float*)d_in[1];
    const float* rank = (const float*)d_in[2];
    float* out = (float*)d_out;

    const int total_threads = BB * (HH / 2) * (WW / 4);   // 1,048,576
    morph2d_kernel<<<total_threads / 256, 256, 0, stream>>>(x, se, rank, out);
}